// Round 9
// baseline (51.555 us; speedup 1.0000x reference)
//
#include <hip/hip_runtime.h>
#include <hip/hip_bf16.h>

#define NO 32
#define HH 64
#define WW 1024
#define LL (HH * WW)
#define BB 8
#define TW 258
#define TSZ 774

typedef _Float16 h2 __attribute__((ext_vector_type(2)));
typedef _Float16 v8h __attribute__((ext_vector_type(8)));
typedef float f32x16 __attribute__((ext_vector_type(16)));
typedef unsigned u32x4v __attribute__((ext_vector_type(4)));

static __device__ __forceinline__ unsigned pku(float a, float b) {
    return __builtin_bit_cast(unsigned, __builtin_amdgcn_cvt_pkrtz(a, b));
}
static __device__ __forceinline__ float lo16f(unsigned u) {
    return (float)__builtin_bit_cast(h2, u).x;
}
static __device__ __forceinline__ float hi16f(unsigned u) {
    return (float)__builtin_bit_cast(h2, u).y;
}

__global__ __launch_bounds__(256, 6) void pnc_kernel(
    const float* __restrict__ x, const float* __restrict__ X,
    const float* __restrict__ A, const float* __restrict__ E,
    const float* __restrict__ M, const float* __restrict__ cw,
    const float* __restrict__ cb, float* __restrict__ out)
{
    __shared__ unsigned tA[TSZ];    // f16x2 [sinA, cosA], 3 rows x 258 cols
    __shared__ unsigned tE[TSZ];    // f16x2 [sinE, cosE]
    __shared__ unsigned tXM[TSZ];   // f16x2 [x, M]

    const int tid = threadIdx.x;
    const int bi  = blockIdx.x;
    const int b   = bi >> 8;          // 256 blocks/image: 64 h x 4 quarters
    const int h   = (bi >> 2) & 63;
    const int wq  = (bi & 3) << 8;
    const int w   = wq + tid;
    const int l   = (h << 10) + w;

    const float* xb = x + b * LL;
    const float* Xb = X + b * LL;
    const float* Ab = A + b * LL;
    const float* Eb = E + b * LL;
    const float* Mb = M + b * LL;

    // ============ issue all global loads up front ============
    float av[4], ev[4], xv[4], mv[4];
    #pragma unroll
    for (int i = 0; i < 4; ++i) {
        const int s = tid + (i << 8);
        const int r = (s >= 2 * TW) ? 2 : ((s >= TW) ? 1 : 0);
        const int c = s - r * TW;
        int gh = h - 1 + r;  gh = min(max(gh, 0), HH - 1);
        int gw = wq - 1 + c; gw = min(max(gw, 0), WW - 1);
        const int gl = (gh << 10) + gw;
        if (i < 3 || s < TSZ) {
            av[i] = Ab[gl]; ev[i] = Eb[gl];
            xv[i] = xb[gl]; mv[i] = Mb[gl];
        } else { av[i] = 0.f; ev[i] = 0.f; xv[i] = 0.f; mv[i] = 0.f; }
    }
    const float Xc = Xb[l];
    // per-lane weight row (o = lane&31), wave-uniformish vector loads
    const int o_ln = tid & 31;
    const float4 wv = ((const float4*)cw)[o_ln];
    const float  bo = cb[o_ln];

    // ============ sincos + LDS tile fill ============
    #pragma unroll
    for (int i = 0; i < 4; ++i) {
        const int s = tid + (i << 8);
        if (i == 3 && s >= TSZ) continue;
        float sa, ca, se, ce;
        __sincosf(av[i], &sa, &ca);
        __sincosf(ev[i], &se, &ce);
        tA[s]  = pku(sa, ca);
        tE[s]  = pku(se, ce);
        tXM[s] = pku(xv[i], mv[i]);
    }
    __syncthreads();

    // ============ center values from tile ============
    const int cl = tid + 1;
    const unsigned cA_ = tA[TW + cl], cE_ = tE[TW + cl], cX_ = tXM[TW + cl];
    const float sAc = lo16f(cA_), cAc = hi16f(cA_);
    const float sEc = lo16f(cE_), cEc = hi16f(cE_);
    const float Mc  = hi16f(cX_);            // exact 0/1 in f16

    // ============ A fragments (weights), validated in R8 ============
    const unsigned a0 = pku(wv.x, wv.y);
    const unsigned a1 = pku(wv.z, wv.w);
    const unsigned a2 = pku(bo, 0.f);
    const bool lol = ((tid & 63) < 32);
    const v8h A1 = __builtin_bit_cast(v8h,
        (u32x4v){lol ? a0 : 0u, lol ? a1 : 0u, lol ? a2 : 0u, 0u});
    const v8h A2 = __builtin_bit_cast(v8h,
        (u32x4v){lol ? 0u : a0, lol ? 0u : a1, lol ? 0u : a2, 0u});

    f32x16 zz;
    #pragma unroll
    for (int i = 0; i < 16; ++i) zz[i] = 0.f;

    // ============ fused tap loop: LDS -> features -> MFMA -> max ============
    f32x16 R1, R2;
    #pragma unroll
    for (int k = 0; k < 9; ++k) {
        const int r  = k / 3;
        const int cc = k % 3;
        const int hh = h + r - 1, ww = w + cc - 1;
        const bool valid = ((unsigned)hh < (unsigned)HH) &
                           ((unsigned)ww < (unsigned)WW);
        const int ts = r * TW + tid + cc;
        const unsigned pa = tA[ts], pe = tE[ts], pxm = tXM[ts];
        const float ux = lo16f(pxm);
        const float um = hi16f(pxm);
        const float mm = valid ? (Mc * um) : 0.f;     // exact 0/1
        const float sAu = lo16f(pa), cAu = hi16f(pa);
        const float sEu = lo16f(pe), cEu = hi16f(pe);
        // angle-difference identities
        const float cA2 = __fmaf_rn(cAu, cAc, sAu * sAc);
        const float sA2 = __fmaf_rn(sAu, cAc, -(cAu * sAc));
        const float cE2 = __fmaf_rn(cEu, cEc, sEu * sEc);
        const float sE2 = __fmaf_rn(sEu, cEc, -(cEu * sEc));
        const float xcA = ux * cA2;
        const float f0 = ux;
        const float f1 = __fmaf_rn(xcA, cE2, -Xc);
        const float f2 = xcA * sE2;
        const float f3 = ux * sA2;
        const v8h Bk = __builtin_bit_cast(v8h,
            (u32x4v){pku(mm * f0, mm * f1), pku(mm * f2, mm * f3),
                     pku(mm, 0.f), 0u});
        const f32x16 D1 = __builtin_amdgcn_mfma_f32_32x32x16_f16(A1, Bk, zz, 0, 0, 0);
        const f32x16 D2 = __builtin_amdgcn_mfma_f32_32x32x16_f16(A2, Bk, zz, 0, 0, 0);
        if (k == 0) { R1 = D1; R2 = D2; }
        else {
            R1 = __builtin_elementwise_max(R1, D1);
            R2 = __builtin_elementwise_max(R2, D2);
        }
    }

    // ============ store: D col=lane&31, row=(reg&3)+8*(reg>>2)+4*(lane>>5)
    const int lane = tid & 63;
    const int wid  = tid >> 6;
    const int c31  = lane & 31;
    const int hi   = lane >> 5;
    float* ob0 = out + (b * NO + hi * 4) * LL + (h << 10) + wq + (wid << 6) + c31;
    #pragma unroll
    for (int i = 0; i < 16; ++i) {
        const int oo = (i & 3) + 8 * (i >> 2);
        __builtin_nontemporal_store(R1[i], ob0 + oo * LL);        // px 0..31
        __builtin_nontemporal_store(R2[i], ob0 + oo * LL + 32);   // px 32..63
    }
}

extern "C" void kernel_launch(void* const* d_in, const int* in_sizes, int n_in,
                              void* d_out, int out_size, void* d_ws, size_t ws_size,
                              hipStream_t stream) {
    const float* x  = (const float*)d_in[0];
    const float* X  = (const float*)d_in[1];
    const float* A  = (const float*)d_in[2];
    const float* E  = (const float*)d_in[3];
    const float* M  = (const float*)d_in[4];
    const float* cw = (const float*)d_in[5];
    const float* cb = (const float*)d_in[6];
    float* out = (float*)d_out;

    pnc_kernel<<<BB * 64 * 4, 256, 0, stream>>>(x, X, A, E, M, cw, cb, out);
}

// Round 10
// 18.786 us; speedup vs baseline: 2.7444x; 2.7444x over previous
//
#include <hip/hip_runtime.h>
#include <hip/hip_bf16.h>

#define NO 32
#define HH 64
#define WW 1024
#define LL (HH * WW)
#define BB 8
#define TW 258
#define TSZ 774

typedef _Float16 h2 __attribute__((ext_vector_type(2)));
typedef _Float16 v8h __attribute__((ext_vector_type(8)));
typedef float f32x16 __attribute__((ext_vector_type(16)));
typedef unsigned u32x4v __attribute__((ext_vector_type(4)));

static __device__ __forceinline__ unsigned pku(float a, float b) {
    return __builtin_bit_cast(unsigned, __builtin_amdgcn_cvt_pkrtz(a, b));
}
static __device__ __forceinline__ float lo16f(unsigned u) {
    return (float)__builtin_bit_cast(h2, u).x;
}
static __device__ __forceinline__ float hi16f(unsigned u) {
    return (float)__builtin_bit_cast(h2, u).y;
}

__global__ __launch_bounds__(256, 4) void pnc_kernel(
    const float* __restrict__ x, const float* __restrict__ X,
    const float* __restrict__ A, const float* __restrict__ E,
    const float* __restrict__ M, const float* __restrict__ cw,
    const float* __restrict__ cb, float* __restrict__ out)
{
    __shared__ unsigned tA[TSZ];    // f16x2 [sinA, cosA], 3 rows x 258 cols
    __shared__ unsigned tE[TSZ];    // f16x2 [sinE, cosE]
    __shared__ unsigned tXM[TSZ];   // f16x2 [x, M]

    const int tid = threadIdx.x;
    const int bi  = blockIdx.x;
    const int b   = bi >> 8;          // 256 blocks/image: 64 h x 4 quarters
    const int h   = (bi >> 2) & 63;
    const int wq  = (bi & 3) << 8;
    const int w   = wq + tid;
    const int l   = (h << 10) + w;

    const float* xb = x + b * LL;
    const float* Xb = X + b * LL;
    const float* Ab = A + b * LL;
    const float* Eb = E + b * LL;
    const float* Mb = M + b * LL;

    // ============ issue all global loads up front ============
    float av[4], ev[4], xv[4], mv[4];
    #pragma unroll
    for (int i = 0; i < 4; ++i) {
        const int s = tid + (i << 8);
        const int r = (s >= 2 * TW) ? 2 : ((s >= TW) ? 1 : 0);
        const int c = s - r * TW;
        int gh = h - 1 + r;  gh = min(max(gh, 0), HH - 1);
        int gw = wq - 1 + c; gw = min(max(gw, 0), WW - 1);
        const int gl = (gh << 10) + gw;
        if (i < 3 || s < TSZ) {
            av[i] = Ab[gl]; ev[i] = Eb[gl];
            xv[i] = xb[gl]; mv[i] = Mb[gl];
        } else { av[i] = 0.f; ev[i] = 0.f; xv[i] = 0.f; mv[i] = 0.f; }
    }
    const float Xc = Xb[l];
    // per-lane weight row (o = lane&31)
    const int o_ln = tid & 31;
    const float4 wv = ((const float4*)cw)[o_ln];
    const float  bo = cb[o_ln];

    // ============ sincos + LDS tile fill ============
    #pragma unroll
    for (int i = 0; i < 4; ++i) {
        const int s = tid + (i << 8);
        if (i == 3 && s >= TSZ) continue;
        float sa, ca, se, ce;
        __sincosf(av[i], &sa, &ca);
        __sincosf(ev[i], &se, &ce);
        tA[s]  = pku(sa, ca);
        tE[s]  = pku(se, ce);
        tXM[s] = pku(xv[i], mv[i]);
    }
    __syncthreads();

    // ============ center values from tile ============
    const int cl = tid + 1;
    const unsigned cA_ = tA[TW + cl], cE_ = tE[TW + cl], cX_ = tXM[TW + cl];
    const float sAc = lo16f(cA_), cAc = hi16f(cA_);
    const float sEc = lo16f(cE_), cEc = hi16f(cE_);
    const float Mc  = hi16f(cX_);            // exact 0/1 in f16

    // ============ A fragments (weights), validated in R8 ============
    const unsigned a0 = pku(wv.x, wv.y);
    const unsigned a1 = pku(wv.z, wv.w);
    const unsigned a2 = pku(bo, 0.f);
    const bool lol = ((tid & 63) < 32);
    const v8h A1 = __builtin_bit_cast(v8h,
        (u32x4v){lol ? a0 : 0u, lol ? a1 : 0u, lol ? a2 : 0u, 0u});
    const v8h A2 = __builtin_bit_cast(v8h,
        (u32x4v){lol ? 0u : a0, lol ? 0u : a1, lol ? 0u : a2, 0u});

    f32x16 zz;
    #pragma unroll
    for (int i = 0; i < 16; ++i) zz[i] = 0.f;

    // ============ fused tap loop: LDS -> features -> MFMA -> max ============
    f32x16 R1, R2;
    #pragma unroll
    for (int k = 0; k < 9; ++k) {
        const int r  = k / 3;
        const int cc = k % 3;
        const int hh = h + r - 1, ww = w + cc - 1;
        const bool valid = ((unsigned)hh < (unsigned)HH) &
                           ((unsigned)ww < (unsigned)WW);
        const int ts = r * TW + tid + cc;
        const unsigned pa = tA[ts], pe = tE[ts], pxm = tXM[ts];
        const float ux = lo16f(pxm);
        const float um = hi16f(pxm);
        const float mm = valid ? (Mc * um) : 0.f;     // exact 0/1
        const float sAu = lo16f(pa), cAu = hi16f(pa);
        const float sEu = lo16f(pe), cEu = hi16f(pe);
        // angle-difference identities
        const float cA2 = __fmaf_rn(cAu, cAc, sAu * sAc);
        const float sA2 = __fmaf_rn(sAu, cAc, -(cAu * sAc));
        const float cE2 = __fmaf_rn(cEu, cEc, sEu * sEc);
        const float sE2 = __fmaf_rn(sEu, cEc, -(cEu * sEc));
        const float xcA = ux * cA2;
        const float f0 = ux;
        const float f1 = __fmaf_rn(xcA, cE2, -Xc);
        const float f2 = xcA * sE2;
        const float f3 = ux * sA2;
        const v8h Bk = __builtin_bit_cast(v8h,
            (u32x4v){pku(mm * f0, mm * f1), pku(mm * f2, mm * f3),
                     pku(mm, 0.f), 0u});
        const f32x16 D1 = __builtin_amdgcn_mfma_f32_32x32x16_f16(A1, Bk, zz, 0, 0, 0);
        const f32x16 D2 = __builtin_amdgcn_mfma_f32_32x32x16_f16(A2, Bk, zz, 0, 0, 0);
        if (k == 0) { R1 = D1; R2 = D2; }
        else {
            R1 = __builtin_elementwise_max(R1, D1);
            R2 = __builtin_elementwise_max(R2, D2);
        }
    }

    // ============ store: D col=lane&31, row=(reg&3)+8*(reg>>2)+4*(lane>>5)
    const int lane = tid & 63;
    const int wid  = tid >> 6;
    const int c31  = lane & 31;
    const int hi   = lane >> 5;
    float* ob0 = out + (b * NO + hi * 4) * LL + (h << 10) + wq + (wid << 6) + c31;
    #pragma unroll
    for (int i = 0; i < 16; ++i) {
        const int oo = (i & 3) + 8 * (i >> 2);
        __builtin_nontemporal_store(R1[i], ob0 + oo * LL);        // px 0..31
        __builtin_nontemporal_store(R2[i], ob0 + oo * LL + 32);   // px 32..63
    }
}

extern "C" void kernel_launch(void* const* d_in, const int* in_sizes, int n_in,
                              void* d_out, int out_size, void* d_ws, size_t ws_size,
                              hipStream_t stream) {
    const float* x  = (const float*)d_in[0];
    const float* X  = (const float*)d_in[1];
    const float* A  = (const float*)d_in[2];
    const float* E  = (const float*)d_in[3];
    const float* M  = (const float*)d_in[4];
    const float* cw = (const float*)d_in[5];
    const float* cb = (const float*)d_in[6];
    float* out = (float*)d_out;

    pnc_kernel<<<BB * 64 * 4, 256, 0, stream>>>(x, X, A, E, M, cw, cb, out);
}